// Round 13
// baseline (1700.977 us; speedup 1.0000x reference)
//
#include <hip/hip_runtime.h>
#include <math.h>

#pragma clang fp contract(fast)

#define S    612
#define TT   8192
#define NB   32
#define SPE  768          // emission row stride in floats (12 per lane, 16B aligned)

typedef float v2f __attribute__((ext_vector_type(2)));

// workspace layout (bytes)
#define WIN_OFF   0        // 640 float4 = 10240 B
#define IV_OFF    10240    // 4 floats
#define EMIS_OFF  16384    // 100*768 floats = 307200 B (pair-reordered, 12/lane)
#define OBS_OFF   327680   // 32*8192 ints = 1 MB

__global__ __launch_bounds__(256) void prep_tables(
    const float* __restrict__ tk, const float* __restrict__ ik,
    float* __restrict__ wIn2, float* __restrict__ Ivec)
{
    int i = blockIdx.x * 256 + threadIdx.x;
    if (i < S) {
        float l0 = tk[3*i], l1 = tk[3*i+1], l2 = tk[3*i+2], l3 = 1.0f;
        float m = fmaxf(fmaxf(l0, l1), fmaxf(l2, l3));
        float e0 = expf(l0-m), e1 = expf(l1-m), e2 = expf(l2-m), e3 = expf(l3-m);
        float inv = 1.0f / (e0+e1+e2+e3);
        wIn2[4*i + 0]              = e0*inv;
        wIn2[4*((i+1)%S) + 1]      = e1*inv;
        wIn2[4*((i+2)%S) + 2]      = e2*inv;
        wIn2[4*((i+3)%S) + 3]      = e3*inv;
    } else if (i < 640) {
        wIn2[4*i+0] = 0.f; wIn2[4*i+1] = 0.f; wIn2[4*i+2] = 0.f; wIn2[4*i+3] = 0.f;
    } else if (i == 640) {
        float l0 = ik[0], l1 = ik[1], l2 = ik[2], l3 = ik[3];
        float m = fmaxf(fmaxf(l0,l1), fmaxf(l2,l3));
        float e0 = expf(l0-m), e1 = expf(l1-m), e2 = expf(l2-m), e3 = expf(l3-m);
        float inv = 1.0f / (e0+e1+e2+e3);
        Ivec[0]=e0*inv; Ivec[1]=e1*inv; Ivec[2]=e2*inv; Ivec[3]=e3*inv;
    }
}

// emission table, stride-5 pair-reordered, 12 floats per lane (pads 10,11 = 0)
__global__ __launch_bounds__(256) void prep_emis(
    const float* __restrict__ ek, float* __restrict__ emisP)
{
    int tid = blockIdx.x * 256 + threadIdx.x;       // tid = o*768 + q
    if (tid >= 100*SPE) return;
    int q = tid % SPE;
    int o = tid / SPE;
    int ln = q / 12, idx = q % 12;
    float val = 0.0f;
    if (ln < 62 && idx < 10) {
        int j = (idx & 1) ? 5 + (idx >> 1) : (idx >> 1);
        int s = ln*10 + j;
        if (s < S-1) {
            int c = o >> 2, le = o & 3;
            if (c == 0) {
                val = 0.25f;
            } else {
                const float* g = ek + s*96 + (c-1)*4;
                float a0=g[0], a1=g[1], a2=g[2], a3=g[3];
                float m = fmaxf(fmaxf(a0,a1), fmaxf(a2,a3));
                float x0=expf(a0-m), x1=expf(a1-m), x2=expf(a2-m), x3=expf(a3-m);
                float inv = 1.0f/(x0+x1+x2+x3);
                float sel = (le==0)?x0:(le==1)?x1:(le==2)?x2:x3;
                val = sel * inv;
            }
        }
    }
    emisP[tid] = val;
}

__global__ __launch_bounds__(256) void extract_obs(
    const float* __restrict__ x, int* __restrict__ obs)
{
    int row  = blockIdx.x * 4 + (threadIdx.x >> 6);
    int lane = threadIdx.x & 63;
    if (row >= NB*TT) return;
    const float* r = x + (size_t)row * 101;
    float acc = r[lane] * (float)lane;
    if (lane < 37) acc += r[64 + lane] * (float)(64 + lane);
    #pragma unroll
    for (int m = 32; m >= 1; m >>= 1) acc += __shfl_xor(acc, m, 64);
    if (lane == 0) obs[row] = (int)(acc + 0.5f);
}

// lane-shift-up-by-1 via DPP wave_shr:1 (VALU pipe); lane 0 -> 0
__device__ __forceinline__ float dpp_up1(float x) {
    int xi = __builtin_bit_cast(int, x);
    int r = __builtin_amdgcn_update_dpp(0, xi, 0x138, 0xF, 0xF, true);
    return __builtin_bit_cast(float, r);
}
template<int CTRL>
__device__ __forceinline__ float dpp_add(float x) {
    int sh = __builtin_amdgcn_update_dpp(0, __builtin_bit_cast(int, x), CTRL, 0xF, 0xF, true);
    return x + __builtin_bit_cast(float, sh);
}
__device__ __forceinline__ float rdlanef(float x, int lane) {
    return __builtin_bit_cast(float, __builtin_amdgcn_readlane(__builtin_bit_cast(int, x), lane));
}

// dual-chain HMM step: chains A and B interleaved statement-by-statement.
// Native v2f ops only -> LLVM scheduler free to interleave at ISA level.
#define HMM_CORE2(EA0,EA1,EA2,EA3,EA4, EB0,EB1,EB2,EB3,EB4)                  \
  {                                                                          \
    float pm1A = dpp_up1(pA[4].y);  float pm1B = dpp_up1(pB[4].y);           \
    float pm2A = dpp_up1(pA[3].y);  float pm2B = dpp_up1(pB[3].y);           \
    float pm3A = dpp_up1(pA[2].y);  float pm3B = dpp_up1(pB[2].y);           \
    float v609A = rdlanef(pA[4].y, 60); float v609B = rdlanef(pB[4].y, 60);  \
    float v610A = rdlanef(pA[0].x, 61); float v610B = rdlanef(pB[0].x, 61);  \
    float v611A = rdlanef(pA[1].x, 61); float v611B = rdlanef(pB[1].x, 61);  \
    pm1A = isl0 ? v611A : pm1A;  pm1B = isl0 ? v611B : pm1B;                 \
    pm2A = isl0 ? v610A : pm2A;  pm2B = isl0 ? v610B : pm2B;                 \
    pm3A = isl0 ? v609A : pm3A;  pm3B = isl0 ? v609B : pm3B;                 \
    v2f B1A; B1A.x = pm1A; B1A.y = pA[4].x;                                  \
    v2f B1B; B1B.x = pm1B; B1B.y = pB[4].x;                                  \
    v2f B2A; B2A.x = pm2A; B2A.y = pA[3].x;                                  \
    v2f B2B; B2B.x = pm2B; B2B.y = pB[3].x;                                  \
    v2f B3A; B3A.x = pm3A; B3A.y = pA[2].x;                                  \
    v2f B3B; B3B.x = pm3B; B3B.y = pB[2].x;                                  \
    v2f c0A = pA[0]*W[0][0] + B1A*W[0][1]   + B2A*W[0][2]   + B3A*W[0][3];   \
    v2f c0B = pB[0]*W[0][0] + B1B*W[0][1]   + B2B*W[0][2]   + B3B*W[0][3];   \
    v2f c1A = pA[1]*W[1][0] + pA[0]*W[1][1] + B1A*W[1][2]   + B2A*W[1][3];   \
    v2f c1B = pB[1]*W[1][0] + pB[0]*W[1][1] + B1B*W[1][2]   + B2B*W[1][3];   \
    v2f c2A = pA[2]*W[2][0] + pA[1]*W[2][1] + pA[0]*W[2][2] + B1A*W[2][3];   \
    v2f c2B = pB[2]*W[2][0] + pB[1]*W[2][1] + pB[0]*W[2][2] + B1B*W[2][3];   \
    v2f c3A = pA[3]*W[3][0] + pA[2]*W[3][1] + pA[1]*W[3][2] + pA[0]*W[3][3]; \
    v2f c3B = pB[3]*W[3][0] + pB[2]*W[3][1] + pB[1]*W[3][2] + pB[0]*W[3][3]; \
    v2f c4A = pA[4]*W[4][0] + pA[3]*W[4][1] + pA[2]*W[4][2] + pA[1]*W[4][3]; \
    v2f c4B = pB[4]*W[4][0] + pB[3]*W[4][1] + pB[2]*W[4][2] + pB[1]*W[4][3]; \
    pA[0] = c0A*(EA0); pB[0] = c0B*(EB0);                                    \
    pA[1] = c1A*(EA1); pB[1] = c1B*(EB1);                                    \
    pA[2] = c2A*(EA2); pB[2] = c2B*(EB2);                                    \
    pA[3] = c3A*(EA3); pB[3] = c3B*(EB3);                                    \
    pA[4] = c4A*(EA4); pB[4] = c4B*(EB4);                                    \
  }

#define HMM_STEP2(JB) HMM_CORE2(ebA[JB][0],ebA[JB][1],ebA[JB][2],ebA[JB][3],ebA[JB][4], \
                                ebB[JB][0],ebB[JB][1],ebB[JB][2],ebB[JB][3],ebB[JB][4])

// dual refill of rotating buffer JB; obs values are wave-uniform scalars
#define PREFETCH2(JB, OVA, OVB)                                              \
  { int _oa = __builtin_amdgcn_readfirstlane(OVA);                           \
    int _ob = __builtin_amdgcn_readfirstlane(OVB);                           \
    const float* _pa = emisP + (size_t)_oa*SPE + 12*l;                       \
    const float* _pb = emisP + (size_t)_ob*SPE + 12*l;                       \
    float4 _qa0 = *(const float4*)_pa;      float4 _qb0 = *(const float4*)_pb;      \
    float4 _qa1 = *(const float4*)(_pa+4);  float4 _qb1 = *(const float4*)(_pb+4);  \
    float2 _qa2 = *(const float2*)(_pa+8);  float2 _qb2 = *(const float2*)(_pb+8);  \
    ebA[JB][0] = (v2f){_qa0.x,_qa0.y}; ebB[JB][0] = (v2f){_qb0.x,_qb0.y};    \
    ebA[JB][1] = (v2f){_qa0.z,_qa0.w}; ebB[JB][1] = (v2f){_qb0.z,_qb0.w};    \
    ebA[JB][2] = (v2f){_qa1.x,_qa1.y}; ebB[JB][2] = (v2f){_qb1.x,_qb1.y};    \
    ebA[JB][3] = (v2f){_qa1.z,_qa1.w}; ebB[JB][3] = (v2f){_qb1.z,_qb1.w};    \
    ebA[JB][4] = (v2f){_qa2.x,_qa2.y}; ebB[JB][4] = (v2f){_qb2.x,_qb2.y}; }

#define STEPJ2(JB, OVA, OVB)  HMM_STEP2(JB); PREFETCH2(JB, OVA, OVB);

#define LOCSUM_(P) ({ v2f _t0 = P[0]+P[1]; v2f _t1 = P[2]+P[3];              \
                      _t0 = _t0 + _t1 + P[4]; _t0.x + _t0.y; })

// dual 16-step renorm block; buffer id = t&3; refills target t+4.
// C1,C2,C3 = obs[t0+4..t0+15], N0 = obs[t0+16..t0+19].
#define GROUP16_2(C1A,C2A,C3A,N0A, C1B,C2B,C3B,N0B)                          \
    STEPJ2(0, (C1A).x, (C1B).x);                                             \
    zlA = dpp_add<0x111>(zlA); zlB = dpp_add<0x111>(zlB);                    \
    STEPJ2(1, (C1A).y, (C1B).y);                                             \
    zlA = dpp_add<0x112>(zlA); zlB = dpp_add<0x112>(zlB);                    \
    STEPJ2(2, (C1A).z, (C1B).z);                                             \
    zlA = dpp_add<0x114>(zlA); zlB = dpp_add<0x114>(zlB);                    \
    STEPJ2(3, (C1A).w, (C1B).w);                                             \
    zlA = dpp_add<0x118>(zlA); zlB = dpp_add<0x118>(zlB);                    \
    STEPJ2(0, (C2A).x, (C2B).x);                                             \
    zlA = dpp_add<0x142>(zlA); zlB = dpp_add<0x142>(zlB);                    \
    STEPJ2(1, (C2A).y, (C2B).y);                                             \
    zlA = dpp_add<0x143>(zlA); zlB = dpp_add<0x143>(zlB);                    \
    STEPJ2(2, (C2A).z, (C2B).z);                                             \
    STEPJ2(3, (C2A).w, (C2B).w);                                             \
    STEPJ2(0, (C3A).x, (C3B).x);                                             \
    STEPJ2(1, (C3A).y, (C3B).y);                                             \
    STEPJ2(2, (C3A).z, (C3B).z);                                             \
    STEPJ2(3, (C3A).w, (C3B).w);                                             \
    STEPJ2(0, (N0A).x, (N0B).x);                                             \
    {                                                                        \
      float zA = rdlanef(zlA, 63), zB = rdlanef(zlB, 63);                    \
      float invA_ = __builtin_amdgcn_rcpf(zA);                               \
      float invB_ = __builtin_amdgcn_rcpf(zB);                               \
      float lgA_ = __logf(zA), lgB_ = __logf(zB);                            \
      STEPJ2(1, (N0A).y, (N0B).y);                                           \
      STEPJ2(2, (N0A).z, (N0B).z);                                           \
      v2f ivA; ivA.x = invA_; ivA.y = invA_;                                 \
      v2f ivB; ivB.x = invB_; ivB.y = invB_;                                 \
      v2f eA0=ebA[3][0]*ivA, eA1=ebA[3][1]*ivA, eA2=ebA[3][2]*ivA;           \
      v2f eA3=ebA[3][3]*ivA, eA4=ebA[3][4]*ivA;                              \
      v2f eB0=ebB[3][0]*ivB, eB1=ebB[3][1]*ivB, eB2=ebB[3][2]*ivB;           \
      v2f eB3=ebB[3][3]*ivB, eB4=ebB[3][4]*ivB;                              \
      HMM_CORE2(eA0,eA1,eA2,eA3,eA4, eB0,eB1,eB2,eB3,eB4);                   \
      PREFETCH2(3, (N0A).w, (N0B).w);                                        \
      llA += lgA_; llB += lgB_;                                              \
    }                                                                        \
    zlA = LOCSUM_(pA); zlB = LOCSUM_(pB);

// one wave handles TWO batches; no LDS; min-occupancy hint frees VGPRs
__global__ __launch_bounds__(64, 1) void forward(
    const float* __restrict__ emisP, const float4* __restrict__ wIn2,
    const float* __restrict__ Ivec, const int* __restrict__ obs,
    float* __restrict__ out)
{
    const int l = threadIdx.x;
    const int bA = blockIdx.x * 2;
    const int bB = bA + 1;
    const bool isl0 = (l == 0);
    const int* obpA = obs + bA * TT;
    const int* obpB = obs + bB * TT;

    // shared per-lane weights, stride-5 pairs
    v2f W[5][4];
    {
        float4 w[10];
        #pragma unroll
        for (int k = 0; k < 10; ++k) w[k] = wIn2[10*l + k];
        #pragma unroll
        for (int j = 0; j < 5; ++j) {
            W[j][0].x = w[j].x; W[j][0].y = w[j+5].x;
            W[j][1].x = w[j].y; W[j][1].y = w[j+5].y;
            W[j][2].x = w[j].z; W[j][2].y = w[j+5].z;
            W[j][3].x = w[j].w; W[j][3].y = w[j+5].w;
        }
    }

    // obs blocks (uniform -> scalar regs)
    int4 c0A, c1A, c2A, c3A, n0A, n1A, n2A, n3A;
    int4 c0B, c1B, c2B, c3B, n0B, n1B, n2B, n3B;
    {
        const int4* a4 = (const int4*)obpA;
        c0A = a4[0]; c1A = a4[1]; c2A = a4[2]; c3A = a4[3];
        n0A = a4[4]; n1A = a4[5]; n2A = a4[6]; n3A = a4[7];
        const int4* b4 = (const int4*)obpB;
        c0B = b4[0]; c1B = b4[1]; c2B = b4[2]; c3B = b4[3];
        n0B = b4[4]; n1B = b4[5]; n2B = b4[6]; n3B = b4[7];
    }

    v2f pA[5], pB[5];
    float llA = 0.0f, llB = 0.0f;
    v2f ebA[4][5], ebB[4][5];

    // t = 0
    {
        int oA = __builtin_amdgcn_readfirstlane(c0A.x);
        const float* ep = emisP + (size_t)oA*SPE + 12*l;
        float e0 = ep[0], e1 = ep[2], e2 = ep[4], e3 = ep[6];
        pA[0].x = isl0 ? e0*Ivec[0] : 0.f;  pA[0].y = 0.f;
        pA[1].x = isl0 ? e1*Ivec[1] : 0.f;  pA[1].y = 0.f;
        pA[2].x = isl0 ? e2*Ivec[2] : 0.f;  pA[2].y = 0.f;
        pA[3].x = isl0 ? e3*Ivec[3] : 0.f;  pA[3].y = 0.f;
        pA[4].x = 0.f; pA[4].y = 0.f;
    }
    {
        int oB = __builtin_amdgcn_readfirstlane(c0B.x);
        const float* ep = emisP + (size_t)oB*SPE + 12*l;
        float e0 = ep[0], e1 = ep[2], e2 = ep[4], e3 = ep[6];
        pB[0].x = isl0 ? e0*Ivec[0] : 0.f;  pB[0].y = 0.f;
        pB[1].x = isl0 ? e1*Ivec[1] : 0.f;  pB[1].y = 0.f;
        pB[2].x = isl0 ? e2*Ivec[2] : 0.f;  pB[2].y = 0.f;
        pB[3].x = isl0 ? e3*Ivec[3] : 0.f;  pB[3].y = 0.f;
        pB[4].x = 0.f; pB[4].y = 0.f;
    }
    float zlA = LOCSUM_(pA);
    float zlB = LOCSUM_(pB);

    // initial buffers for t = 1..4 (ids 1,2,3,0)
    PREFETCH2(1, c0A.y, c0B.y);
    PREFETCH2(2, c0A.z, c0B.z);
    PREFETCH2(3, c0A.w, c0B.w);
    PREFETCH2(0, c1A.x, c1B.x);

    // prologue: steps t = 1..15 (fold at t=15); refill target t+4
    STEPJ2(1, c1A.y, c1B.y); zlA = dpp_add<0x111>(zlA); zlB = dpp_add<0x111>(zlB);
    STEPJ2(2, c1A.z, c1B.z); zlA = dpp_add<0x112>(zlA); zlB = dpp_add<0x112>(zlB);
    STEPJ2(3, c1A.w, c1B.w); zlA = dpp_add<0x114>(zlA); zlB = dpp_add<0x114>(zlB);
    STEPJ2(0, c2A.x, c2B.x); zlA = dpp_add<0x118>(zlA); zlB = dpp_add<0x118>(zlB);
    STEPJ2(1, c2A.y, c2B.y); zlA = dpp_add<0x142>(zlA); zlB = dpp_add<0x142>(zlB);
    STEPJ2(2, c2A.z, c2B.z); zlA = dpp_add<0x143>(zlA); zlB = dpp_add<0x143>(zlB);
    STEPJ2(3, c2A.w, c2B.w);
    STEPJ2(0, c3A.x, c3B.x);
    STEPJ2(1, c3A.y, c3B.y);
    STEPJ2(2, c3A.z, c3B.z);
    STEPJ2(3, c3A.w, c3B.w);
    STEPJ2(0, n0A.x, n0B.x);
    {
      float zA = rdlanef(zlA, 63), zB = rdlanef(zlB, 63);
      float invA_ = __builtin_amdgcn_rcpf(zA);
      float invB_ = __builtin_amdgcn_rcpf(zB);
      float lgA_ = __logf(zA), lgB_ = __logf(zB);
      STEPJ2(1, n0A.y, n0B.y);
      STEPJ2(2, n0A.z, n0B.z);
      v2f ivA; ivA.x = invA_; ivA.y = invA_;
      v2f ivB; ivB.x = invB_; ivB.y = invB_;
      v2f eA0=ebA[3][0]*ivA, eA1=ebA[3][1]*ivA, eA2=ebA[3][2]*ivA;
      v2f eA3=ebA[3][3]*ivA, eA4=ebA[3][4]*ivA;
      v2f eB0=ebB[3][0]*ivB, eB1=ebB[3][1]*ivB, eB2=ebB[3][2]*ivB;
      v2f eB3=ebB[3][3]*ivB, eB4=ebB[3][4]*ivB;
      HMM_CORE2(eA0,eA1,eA2,eA3,eA4, eB0,eB1,eB2,eB3,eB4);
      PREFETCH2(3, n0A.w, n0B.w);
      llA += lgA_; llB += lgB_;
    }
    zlA = LOCSUM_(pA); zlB = LOCSUM_(pB);

    // main: 511 blocks of 16 steps (t = 16..8191)
    #pragma unroll 1
    for (int g = 1; g < 512; ++g) {
        c1A = n1A; c2A = n2A; c3A = n3A;
        c1B = n1B; c2B = n2B; c3B = n3B;
        int off = (g < 511) ? (g+1)*16 : 8176;
        const int4* a4 = (const int4*)(obpA + off);
        n0A = a4[0]; n1A = a4[1]; n2A = a4[2]; n3A = a4[3];
        const int4* b4 = (const int4*)(obpB + off);
        n0B = b4[0]; n1B = b4[1]; n2B = b4[2]; n3B = b4[3];
        GROUP16_2(c1A, c2A, c3A, n0A, c1B, c2B, c3B, n0B);
    }

    // final: z of the last block
    {
        float zfA = zlA, zfB = zlB;
        zfA = dpp_add<0x111>(zfA); zfB = dpp_add<0x111>(zfB);
        zfA = dpp_add<0x112>(zfA); zfB = dpp_add<0x112>(zfB);
        zfA = dpp_add<0x114>(zfA); zfB = dpp_add<0x114>(zfB);
        zfA = dpp_add<0x118>(zfA); zfB = dpp_add<0x118>(zfB);
        zfA = dpp_add<0x142>(zfA); zfB = dpp_add<0x142>(zfB);
        zfA = dpp_add<0x143>(zfA); zfB = dpp_add<0x143>(zfB);
        llA += __logf(rdlanef(zfA, 63));
        llB += __logf(rdlanef(zfB, 63));
    }
    if (isl0) { out[bA] = llA; out[bB] = llB; }
}

extern "C" void kernel_launch(void* const* d_in, const int* in_sizes, int n_in,
                              void* d_out, int out_size, void* d_ws, size_t ws_size,
                              hipStream_t stream)
{
    const float* x  = (const float*)d_in[0];   // inputs [32,8192,101]
    const float* ik = (const float*)d_in[1];   // init_kernel [4]
    const float* tk = (const float*)d_in[2];   // transition_kernel [1836]
    const float* ek = (const float*)d_in[3];   // emission_kernel [58656]
    float* out = (float*)d_out;

    char* ws = (char*)d_ws;
    float*  wIn2  = (float*)(ws + WIN_OFF);
    float*  Ivec  = (float*)(ws + IV_OFF);
    float*  emisP = (float*)(ws + EMIS_OFF);
    int*    obs   = (int*)(ws + OBS_OFF);

    hipLaunchKernelGGL(prep_tables, dim3(3), dim3(256), 0, stream, tk, ik, wIn2, Ivec);
    hipLaunchKernelGGL(prep_emis, dim3((100*SPE + 255)/256), dim3(256), 0, stream, ek, emisP);
    hipLaunchKernelGGL(extract_obs, dim3((NB*TT + 3)/4), dim3(256), 0, stream, x, obs);
    hipLaunchKernelGGL(forward, dim3(NB/2), dim3(64), 0, stream,
                       emisP, (const float4*)wIn2, Ivec, obs, out);
}

// Round 14
// 720.707 us; speedup vs baseline: 2.3602x; 2.3602x over previous
//
#include <hip/hip_runtime.h>
#include <math.h>

#pragma clang fp contract(fast)

#define S    612
#define TT   8192
#define NB   32
#define SPE2 512          // floats per emission row per wave (8 per lane)
#define CW   354          // computed width per wave: 48 halo + 306 owned

typedef float v2f __attribute__((ext_vector_type(2)));

// workspace layout (bytes)
#define WIN_OFF   0        // 640 float4 = 10240
#define IV_OFF    10240    // 4 floats
#define EMIS_OFF  16384    // 2*100*512 floats = 409600 -> ends 425984
#define OBS_OFF   425984   // 32*8192 ints = 1 MB

// incoming-weight table: wIn2[t] = (in0,in1,in2,in3), in_k = row((t-k)%S)[k]
__global__ __launch_bounds__(256) void prep_tables(
    const float* __restrict__ tk, const float* __restrict__ ik,
    float* __restrict__ wIn2, float* __restrict__ Ivec)
{
    int i = blockIdx.x * 256 + threadIdx.x;
    if (i < S) {
        float l0 = tk[3*i], l1 = tk[3*i+1], l2 = tk[3*i+2], l3 = 1.0f;
        float m = fmaxf(fmaxf(l0, l1), fmaxf(l2, l3));
        float e0 = expf(l0-m), e1 = expf(l1-m), e2 = expf(l2-m), e3 = expf(l3-m);
        float inv = 1.0f / (e0+e1+e2+e3);
        wIn2[4*i + 0]              = e0*inv;
        wIn2[4*((i+1)%S) + 1]      = e1*inv;
        wIn2[4*((i+2)%S) + 2]      = e2*inv;
        wIn2[4*((i+3)%S) + 3]      = e3*inv;
    } else if (i < 640) {
        wIn2[4*i+0] = 0.f; wIn2[4*i+1] = 0.f; wIn2[4*i+2] = 0.f; wIn2[4*i+3] = 0.f;
    } else if (i == 640) {
        float l0 = ik[0], l1 = ik[1], l2 = ik[2], l3 = ik[3];
        float m = fmaxf(fmaxf(l0,l1), fmaxf(l2,l3));
        float e0 = expf(l0-m), e1 = expf(l1-m), e2 = expf(l2-m), e3 = expf(l3-m);
        float inv = 1.0f / (e0+e1+e2+e3);
        Ivec[0]=e0*inv; Ivec[1]=e1*inv; Ivec[2]=e2*inv; Ivec[3]=e3*inv;
    }
}

// per-wave emission tables: wave wv, row o, lane ln holds 8 floats:
// [E(c0),E(c3),E(c1),E(c4),E(c2),E(c5),0,0] for local positions 6*ln+c,
// state s = (start_wv + pos) % 612, start = {564, 258}; zero for pads/state 611.
__global__ __launch_bounds__(256) void prep_emis2(
    const float* __restrict__ ek, float* __restrict__ emisP)
{
    int tid = blockIdx.x * 256 + threadIdx.x;
    if (tid >= 2*100*SPE2) return;
    int wv = tid / (100*SPE2);
    int r  = tid % (100*SPE2);
    int o  = r / SPE2;
    int q8 = r % SPE2;
    int ln = q8 >> 3, j = q8 & 7;
    float val = 0.0f;
    if (j < 6) {
        int c = (j >> 1) + ((j & 1) ? 3 : 0);
        int pos = 6*ln + c;
        if (pos < CW) {
            int s = ((wv ? 258 : 564) + pos) % S;
            if (s < S-1) {
                int ctx = o >> 2, le = o & 3;
                if (ctx == 0) {
                    val = 0.25f;
                } else {
                    const float* g = ek + s*96 + (ctx-1)*4;
                    float a0=g[0], a1=g[1], a2=g[2], a3=g[3];
                    float m = fmaxf(fmaxf(a0,a1), fmaxf(a2,a3));
                    float x0=expf(a0-m), x1=expf(a1-m), x2=expf(a2-m), x3=expf(a3-m);
                    float inv = 1.0f/(x0+x1+x2+x3);
                    val = ((le==0)?x0:(le==1)?x1:(le==2)?x2:x3) * inv;
                }
            }
        }
    }
    emisP[tid] = val;
}

__global__ __launch_bounds__(256) void extract_obs(
    const float* __restrict__ x, int* __restrict__ obs)
{
    int row  = blockIdx.x * 4 + (threadIdx.x >> 6);
    int lane = threadIdx.x & 63;
    if (row >= NB*TT) return;
    const float* r = x + (size_t)row * 101;
    float acc = r[lane] * (float)lane;
    if (lane < 37) acc += r[64 + lane] * (float)(64 + lane);
    #pragma unroll
    for (int m = 32; m >= 1; m >>= 1) acc += __shfl_xor(acc, m, 64);
    if (lane == 0) obs[row] = (int)(acc + 0.5f);
}

__device__ __forceinline__ float dpp_up1(float x) {
    int xi = __builtin_bit_cast(int, x);
    int r = __builtin_amdgcn_update_dpp(0, xi, 0x138, 0xF, 0xF, true);
    return __builtin_bit_cast(float, r);
}
template<int CTRL>
__device__ __forceinline__ float dpp_add(float x) {
    int sh = __builtin_amdgcn_update_dpp(0, __builtin_bit_cast(int, x), CTRL, 0xF, 0xF, true);
    return x + __builtin_bit_cast(float, sh);
}
__device__ __forceinline__ float rdlanef(float x, int lane) {
    return __builtin_bit_cast(float, __builtin_amdgcn_readlane(__builtin_bit_cast(int, x), lane));
}

// 3-pair core: pairs p[j] = (a_j, a_{j+3}) over 6 local positions per lane.
// Lane 0's missing predecessors are DPP zeros -> garbage creeps into the halo
// only; no wrap patch needed.
#define CORE(E0,E1,E2)                                                       \
  {                                                                          \
    float pm1 = dpp_up1(p[2].y);                                             \
    float pm2 = dpp_up1(p[1].y);                                             \
    float pm3 = dpp_up1(p[0].y);                                             \
    v2f B1; B1.x = pm1; B1.y = p[2].x;                                       \
    v2f B2; B2.x = pm2; B2.y = p[1].x;                                       \
    v2f B3; B3.x = pm3; B3.y = p[0].x;                                       \
    v2f c0 = p[0]*W[0][0] + B1*W[0][1]   + B2*W[0][2] + B3*W[0][3];          \
    v2f c1 = p[1]*W[1][0] + p[0]*W[1][1] + B1*W[1][2] + B2*W[1][3];          \
    v2f c2 = p[2]*W[2][0] + p[1]*W[2][1] + p[0]*W[2][2] + B1*W[2][3];        \
    p[0] = c0*(E0); p[1] = c1*(E1); p[2] = c2*(E2);                          \
  }

#define PFX(JB, OV)                                                          \
  { int _oo = __builtin_amdgcn_readfirstlane(OV);                            \
    const float* _pp = ebase + _oo*SPE2 + 8*l;                               \
    float4 _q = *(const float4*)_pp;                                         \
    float2 _r = *(const float2*)(_pp+4);                                     \
    eb[JB][0] = (v2f){_q.x,_q.y};                                            \
    eb[JB][1] = (v2f){_q.z,_q.w};                                            \
    eb[JB][2] = (v2f){_r.x,_r.y}; }

#define STEPX(JB, OV)  CORE(eb[JB][0],eb[JB][1],eb[JB][2]); PFX(JB, OV);

// boundary: masked z reduce, halo+z exchange through LDS, global renorm
#define BOUNDARY()                                                           \
  { v2f _t = p[0] + p[1]; _t = _t + p[2];                                    \
    float zr = (_t.x + _t.y) * zmask;                                        \
    zr = dpp_add<0x111>(zr); zr = dpp_add<0x112>(zr);                        \
    zr = dpp_add<0x114>(zr); zr = dpp_add<0x118>(zr);                        \
    zr = dpp_add<0x142>(zr); zr = dpp_add<0x143>(zr);                        \
    if (l >= 51 && l <= 58) {                                                \
      float* _o = &box[par][wv][6*(l-51)];                                   \
      _o[0]=p[0].x; _o[1]=p[1].x; _o[2]=p[2].x;                              \
      _o[3]=p[0].y; _o[4]=p[1].y; _o[5]=p[2].y;                              \
    }                                                                        \
    if (l == 63) box[par][wv][48] = zr;                                      \
    __syncthreads();                                                         \
    float zo = box[par][1-wv][48];                                           \
    if (l < 8) {                                                             \
      const float* _q = &box[par][1-wv][6*l];                                \
      p[0].x=_q[0]; p[1].x=_q[1]; p[2].x=_q[2];                              \
      p[0].y=_q[3]; p[1].y=_q[4]; p[2].y=_q[5];                              \
    }                                                                        \
    float z = rdlanef(zr, 63) + zo;                                          \
    float inv_ = __builtin_amdgcn_rcpf(z);                                   \
    ll += __logf(z);                                                         \
    v2f _iv; _iv.x = inv_; _iv.y = inv_;                                     \
    p[0] = p[0]*_iv; p[1] = p[1]*_iv; p[2] = p[2]*_iv;                       \
    par ^= 1; }

// 2 waves per block, 1 batch per block; wave wv owns 306 states + 48 halo
__global__ __launch_bounds__(128, 1) void forward(
    const float* __restrict__ emisP, const float4* __restrict__ wIn2,
    const float* __restrict__ Ivec, const int* __restrict__ obs,
    float* __restrict__ out)
{
    const int tid = threadIdx.x;
    const int l   = tid & 63;
    const int wv  = tid >> 6;
    const int b   = blockIdx.x;
    const int* obp = obs + b * TT;
    const float* ebase = emisP + (size_t)wv * 100 * SPE2;
    __shared__ float box[2][2][52];

    // per-lane weights: W[j][k] = (in_k(state at pos 6l+j), in_k(pos 6l+j+3))
    v2f W[3][4];
    {
        float4 wq[6];
        int st = wv ? 258 : 564;
        #pragma unroll
        for (int c = 0; c < 6; ++c) {
            int pos = 6*l + c;
            if (pos < CW) wq[c] = wIn2[(st + pos) % S];
            else          wq[c] = make_float4(0.f, 0.f, 0.f, 0.f);
        }
        #pragma unroll
        for (int j = 0; j < 3; ++j) {
            W[j][0].x = wq[j].x;  W[j][0].y = wq[j+3].x;
            W[j][1].x = wq[j].y;  W[j][1].y = wq[j+3].y;
            W[j][2].x = wq[j].z;  W[j][2].y = wq[j+3].z;
            W[j][3].x = wq[j].w;  W[j][3].y = wq[j+3].w;
        }
    }
    const float zmask = (l >= 8 && l <= 58) ? 1.0f : 0.0f;

    // obs blocks (uniform): q0 + a1..a3 = B(0); b0..b3 = B(1)
    int4 q0, a1, a2, a3, b0, b1, b2, b3;
    {
        const int4* o4 = (const int4*)obp;
        q0 = o4[0]; a1 = o4[1]; a2 = o4[2]; a3 = o4[3];
        b0 = o4[4]; b1 = o4[5]; b2 = o4[6]; b3 = o4[7];
    }

    v2f p[3];
    p[0] = (v2f){0.f,0.f}; p[1] = (v2f){0.f,0.f}; p[2] = (v2f){0.f,0.f};
    float ll = 0.0f;
    v2f eb[4][3];
    int par = 0;

    // t = 0: states 0..3 live at wave0 positions 48..51 (lane 8, c=0,3,1,2)
    {
        int o0 = __builtin_amdgcn_readfirstlane(q0.x);
        const float* pp = ebase + o0*SPE2 + 8*l;
        float4 q = *(const float4*)pp;
        float2 r2 = *(const float2*)(pp+4);
        if (wv == 0 && l == 8) {
            p[0].x = q.x  * Ivec[0];   // state 0
            p[0].y = q.y  * Ivec[3];   // state 3
            p[1].x = q.z  * Ivec[1];   // state 1
            p[2].x = r2.x * Ivec[2];   // state 2
        }
    }

    BOUNDARY();   // t=0: z0, log, renorm, (zero) halo import

    // initial emission buffers for steps 1..4 (ids 1,2,3,0)
    PFX(1, q0.y); PFX(2, q0.z); PFX(3, q0.w); PFX(0, a1.x);

    // windows g = 0..510: steps 16g+1 .. 16g+16, boundary after each
    #pragma unroll 1
    for (int g = 0; g < 511; ++g) {
        STEPX(1, a1.y); STEPX(2, a1.z); STEPX(3, a1.w); STEPX(0, a2.x);
        STEPX(1, a2.y); STEPX(2, a2.z); STEPX(3, a2.w); STEPX(0, a3.x);
        STEPX(1, a3.y); STEPX(2, a3.z); STEPX(3, a3.w); STEPX(0, b0.x);
        STEPX(1, b0.y); STEPX(2, b0.z); STEPX(3, b0.w); STEPX(0, b1.x);
        BOUNDARY();
        a1 = b1; a2 = b2; a3 = b3;
        int off = 16*(g+2); if (off > TT-16) off = TT-16;
        const int4* o4 = (const int4*)(obp + off);
        b0 = o4[0]; b1 = o4[1]; b2 = o4[2]; b3 = o4[3];
    }

    // final partial window: steps 8177..8191 (15 steps; tail prefetches unused)
    STEPX(1, a1.y); STEPX(2, a1.z); STEPX(3, a1.w); STEPX(0, a2.x);
    STEPX(1, a2.y); STEPX(2, a2.z); STEPX(3, a2.w); STEPX(0, a3.x);
    STEPX(1, a3.y); STEPX(2, a3.z); STEPX(3, a3.w); STEPX(0, b0.x);
    STEPX(1, b0.y); STEPX(2, b0.z); STEPX(3, b0.w);

    // final z (cross-wave)
    {
        v2f t = p[0] + p[1]; t = t + p[2];
        float zr = (t.x + t.y) * zmask;
        zr = dpp_add<0x111>(zr); zr = dpp_add<0x112>(zr);
        zr = dpp_add<0x114>(zr); zr = dpp_add<0x118>(zr);
        zr = dpp_add<0x142>(zr); zr = dpp_add<0x143>(zr);
        if (l == 63) box[par][wv][48] = zr;
        __syncthreads();
        float zo = box[par][1-wv][48];
        ll += __logf(rdlanef(zr, 63) + zo);
    }
    if (tid == 0) out[b] = ll;
}

extern "C" void kernel_launch(void* const* d_in, const int* in_sizes, int n_in,
                              void* d_out, int out_size, void* d_ws, size_t ws_size,
                              hipStream_t stream)
{
    const float* x  = (const float*)d_in[0];   // inputs [32,8192,101]
    const float* ik = (const float*)d_in[1];   // init_kernel [4]
    const float* tk = (const float*)d_in[2];   // transition_kernel [1836]
    const float* ek = (const float*)d_in[3];   // emission_kernel [58656]
    float* out = (float*)d_out;

    char* ws = (char*)d_ws;
    float*  wIn2  = (float*)(ws + WIN_OFF);
    float*  Ivec  = (float*)(ws + IV_OFF);
    float*  emisP = (float*)(ws + EMIS_OFF);
    int*    obs   = (int*)(ws + OBS_OFF);

    hipLaunchKernelGGL(prep_tables, dim3(3), dim3(256), 0, stream, tk, ik, wIn2, Ivec);
    hipLaunchKernelGGL(prep_emis2, dim3((2*100*SPE2 + 255)/256), dim3(256), 0, stream,
                       ek, emisP);
    hipLaunchKernelGGL(extract_obs, dim3((NB*TT + 3)/4), dim3(256), 0, stream, x, obs);
    hipLaunchKernelGGL(forward, dim3(NB), dim3(128), 0, stream,
                       emisP, (const float4*)wIn2, Ivec, obs, out);
}

// Round 15
// 641.344 us; speedup vs baseline: 2.6522x; 1.1237x over previous
//
#include <hip/hip_runtime.h>
#include <math.h>

#pragma clang fp contract(fast)

#define S    612
#define TT   8192
#define NB   32
#define SPW  256          // per-wave emission row width in floats (4 per lane)

typedef float v2f __attribute__((ext_vector_type(2)));

// workspace layout (bytes)
#define WIN_OFF   0        // 640 float4 = 10240
#define IV_OFF    10240    // 4 floats
#define EMIS_OFF  16384    // 4*100*256 floats = 409600 -> ends 425984
#define OBS_OFF   425984   // 32*8192 ints = 1 MB

// incoming-weight table: wIn2[t] = (in0,in1,in2,in3), in_k = row((t-k)%S)[k]
__global__ __launch_bounds__(256) void prep_tables(
    const float* __restrict__ tk, const float* __restrict__ ik,
    float* __restrict__ wIn2, float* __restrict__ Ivec)
{
    int i = blockIdx.x * 256 + threadIdx.x;
    if (i < S) {
        float l0 = tk[3*i], l1 = tk[3*i+1], l2 = tk[3*i+2], l3 = 1.0f;
        float m = fmaxf(fmaxf(l0, l1), fmaxf(l2, l3));
        float e0 = expf(l0-m), e1 = expf(l1-m), e2 = expf(l2-m), e3 = expf(l3-m);
        float inv = 1.0f / (e0+e1+e2+e3);
        wIn2[4*i + 0]              = e0*inv;
        wIn2[4*((i+1)%S) + 1]      = e1*inv;
        wIn2[4*((i+2)%S) + 2]      = e2*inv;
        wIn2[4*((i+3)%S) + 3]      = e3*inv;
    } else if (i < 640) {
        wIn2[4*i+0] = 0.f; wIn2[4*i+1] = 0.f; wIn2[4*i+2] = 0.f; wIn2[4*i+3] = 0.f;
    } else if (i == 640) {
        float l0 = ik[0], l1 = ik[1], l2 = ik[2], l3 = ik[3];
        float m = fmaxf(fmaxf(l0,l1), fmaxf(l2,l3));
        float e0 = expf(l0-m), e1 = expf(l1-m), e2 = expf(l2-m), e3 = expf(l3-m);
        float inv = 1.0f / (e0+e1+e2+e3);
        Ivec[0]=e0*inv; Ivec[1]=e1*inv; Ivec[2]=e2*inv; Ivec[3]=e3*inv;
    }
}

// per-wave emission tables; wave wv, row o, lane ln holds float4
// (E(pos0),E(pos2),E(pos1),E(pos3)) for local pos 4*ln+c,
// state s = (haloBase_wv + pos) % 612; zero for pads / state 611.
__global__ __launch_bounds__(256) void prep_emis4(
    const float* __restrict__ ek, float* __restrict__ emisP)
{
    int tid = blockIdx.x * 256 + threadIdx.x;
    if (tid >= 4*100*SPW) return;
    int wv = tid / (100*SPW);
    int r  = tid % (100*SPW);
    int o  = r / SPW;
    int q  = r % SPW;
    int ln = q >> 2, j = q & 3;
    int c = (j==0) ? 0 : (j==1) ? 2 : (j==2) ? 1 : 3;
    int pos = 4*ln + c;
    int haloBase = (wv==0) ? 564 : (wv==1) ? 104 : (wv==2) ? 256 : 408;
    int CWv = (wv==3) ? 204 : 200;
    float val = 0.0f;
    if (pos < CWv) {
        int s = (haloBase + pos) % S;
        if (s < S-1) {
            int ctx = o >> 2, le = o & 3;
            if (ctx == 0) {
                val = 0.25f;
            } else {
                const float* g = ek + s*96 + (ctx-1)*4;
                float a0=g[0], a1=g[1], a2=g[2], a3=g[3];
                float m = fmaxf(fmaxf(a0,a1), fmaxf(a2,a3));
                float x0=expf(a0-m), x1=expf(a1-m), x2=expf(a2-m), x3=expf(a3-m);
                float inv = 1.0f/(x0+x1+x2+x3);
                val = ((le==0)?x0:(le==1)?x1:(le==2)?x2:x3) * inv;
            }
        }
    }
    emisP[tid] = val;
}

__global__ __launch_bounds__(256) void extract_obs(
    const float* __restrict__ x, int* __restrict__ obs)
{
    int row  = blockIdx.x * 4 + (threadIdx.x >> 6);
    int lane = threadIdx.x & 63;
    if (row >= NB*TT) return;
    const float* r = x + (size_t)row * 101;
    float acc = r[lane] * (float)lane;
    if (lane < 37) acc += r[64 + lane] * (float)(64 + lane);
    #pragma unroll
    for (int m = 32; m >= 1; m >>= 1) acc += __shfl_xor(acc, m, 64);
    if (lane == 0) obs[row] = (int)(acc + 0.5f);
}

__device__ __forceinline__ float dpp_up1(float x) {
    int xi = __builtin_bit_cast(int, x);
    int r = __builtin_amdgcn_update_dpp(0, xi, 0x138, 0xF, 0xF, true);
    return __builtin_bit_cast(float, r);
}
template<int CTRL>
__device__ __forceinline__ float dpp_add(float x) {
    int sh = __builtin_amdgcn_update_dpp(0, __builtin_bit_cast(int, x), CTRL, 0xF, 0xF, true);
    return x + __builtin_bit_cast(float, sh);
}

// 2-pair core: p[0]=(pos0,pos2), p[1]=(pos1,pos3) per lane (stride-2 pairs).
// Lane 0's missing predecessors are DPP zeros -> garbage creeps into the
// 48-halo only (3 positions/step, 16 steps); no wrap patch needed.
#define CORE(E0,E1)                                                          \
  {                                                                          \
    float pm1 = dpp_up1(p[1].y);        /* pos 4l-1 */                       \
    float pm2 = dpp_up1(p[0].y);        /* pos 4l-2 */                       \
    float pm3 = dpp_up1(p[1].x);        /* pos 4l-3 */                       \
    v2f B1; B1.x = pm1; B1.y = p[1].x;                                       \
    v2f B2; B2.x = pm2; B2.y = p[0].x;                                       \
    v2f B3; B3.x = pm3; B3.y = pm1;                                          \
    v2f c0 = p[0]*W[0][0] + B1*W[0][1]   + B2*W[0][2] + B3*W[0][3];          \
    v2f c1 = p[1]*W[1][0] + p[0]*W[1][1] + B1*W[1][2] + B2*W[1][3];          \
    p[0] = c0*(E0); p[1] = c1*(E1);                                          \
  }

#define PFX(JB, OV)                                                          \
  { int _oo = __builtin_amdgcn_readfirstlane(OV);                            \
    float4 _q = *(const float4*)(ebase + _oo*SPW + 4*l);                     \
    eb[JB][0] = (v2f){_q.x,_q.y};                                            \
    eb[JB][1] = (v2f){_q.z,_q.w}; }

#define STEPX(JB, OV)  CORE(eb[JB][0],eb[JB][1]); PFX(JB, OV);

// boundary: masked z reduce, 4-wave ring halo exchange via LDS, global renorm
#define BOUNDARY()                                                           \
  { v2f _t = p[0] + p[1];                                                    \
    float zr = (_t.x + _t.y) * zmask;                                        \
    zr = dpp_add<0x111>(zr); zr = dpp_add<0x112>(zr);                        \
    zr = dpp_add<0x114>(zr); zr = dpp_add<0x118>(zr);                        \
    zr = dpp_add<0x142>(zr); zr = dpp_add<0x143>(zr);                        \
    if (l >= exBase && l < exBase + 12) {                                    \
      float* _o = &box[par][wv][4*(l - exBase)];                             \
      _o[0]=p[0].x; _o[1]=p[1].x; _o[2]=p[0].y; _o[3]=p[1].y;                \
    }                                                                        \
    if (l == 63) box[par][wv][48] = zr;                                      \
    __syncthreads();                                                         \
    if (l < 12) {                                                            \
      const float* _q = &box[par][(wv+3)&3][4*l];                            \
      p[0].x=_q[0]; p[1].x=_q[1]; p[0].y=_q[2]; p[1].y=_q[3];                \
    }                                                                        \
    float z = ((box[par][0][48] + box[par][1][48]) +                         \
               (box[par][2][48] + box[par][3][48]));                         \
    float inv_ = __builtin_amdgcn_rcpf(z);                                   \
    ll += __logf(z);                                                         \
    v2f _iv; _iv.x = inv_; _iv.y = inv_;                                     \
    p[0] = p[0]*_iv; p[1] = p[1]*_iv;                                        \
    par ^= 1; }

// 4 waves per block, 1 batch per block; wave wv owns 152/156 states + 48 halo
__global__ __launch_bounds__(256, 1) void forward(
    const float* __restrict__ emisP, const float4* __restrict__ wIn2,
    const float* __restrict__ Ivec, const int* __restrict__ obs,
    float* __restrict__ out)
{
    const int tid = threadIdx.x;
    const int l   = tid & 63;
    const int wv  = tid >> 6;
    const int b   = blockIdx.x;
    const int* obp = obs + b * TT;
    const int haloBase = (wv==0) ? 564 : (wv==1) ? 104 : (wv==2) ? 256 : 408;
    const int owned    = (wv==3) ? 156 : 152;
    const int CWv      = owned + 48;
    const int exBase   = owned >> 2;            // 38 or 39
    const float* ebase = emisP + (size_t)wv * 100 * SPW;
    __shared__ float box[2][4][49];

    // per-lane weights: W[pair][k] = (in_k(pos 4l+pair), in_k(pos 4l+pair+2))
    v2f W[2][4];
    {
        float4 wq[4];
        #pragma unroll
        for (int c = 0; c < 4; ++c) {
            int pos = 4*l + c;
            if (pos < CWv) wq[c] = wIn2[(haloBase + pos) % S];
            else           wq[c] = make_float4(0.f, 0.f, 0.f, 0.f);
        }
        W[0][0].x = wq[0].x;  W[0][0].y = wq[2].x;
        W[0][1].x = wq[0].y;  W[0][1].y = wq[2].y;
        W[0][2].x = wq[0].z;  W[0][2].y = wq[2].z;
        W[0][3].x = wq[0].w;  W[0][3].y = wq[2].w;
        W[1][0].x = wq[1].x;  W[1][0].y = wq[3].x;
        W[1][1].x = wq[1].y;  W[1][1].y = wq[3].y;
        W[1][2].x = wq[1].z;  W[1][2].y = wq[3].z;
        W[1][3].x = wq[1].w;  W[1][3].y = wq[3].w;
    }
    const float zmask = (l >= 12 && l <= ((wv==3) ? 50 : 49)) ? 1.0f : 0.0f;

    // obs blocks (uniform scalar regs)
    int4 q0, a1, a2, a3, b0, b1, b2, b3;
    {
        const int4* o4 = (const int4*)obp;
        q0 = o4[0]; a1 = o4[1]; a2 = o4[2]; a3 = o4[3];
        b0 = o4[4]; b1 = o4[5]; b2 = o4[6]; b3 = o4[7];
    }

    v2f p[2];
    p[0] = (v2f){0.f,0.f}; p[1] = (v2f){0.f,0.f};
    float ll = 0.0f;
    v2f eb[4][2];
    int par = 0;

    // t = 0: states 0..3 live at wave0 local pos 48..51 (lane 12)
    {
        int o0 = __builtin_amdgcn_readfirstlane(q0.x);
        float4 q = *(const float4*)(ebase + o0*SPW + 4*l);
        if (wv == 0 && l == 12) {
            p[0].x = q.x * Ivec[0];   // state 0 (pos 48)
            p[0].y = q.y * Ivec[2];   // state 2 (pos 50)
            p[1].x = q.z * Ivec[1];   // state 1 (pos 49)
            p[1].y = q.w * Ivec[3];   // state 3 (pos 51)
        }
    }

    BOUNDARY();   // t=0: z0, log, renorm, (zero) halo import

    // initial emission buffers for steps 1..4 (ids 1,2,3,0)
    PFX(1, q0.y); PFX(2, q0.z); PFX(3, q0.w); PFX(0, a1.x);

    // windows g = 0..510: steps 16g+1 .. 16g+16, boundary after each
    #pragma unroll 1
    for (int g = 0; g < 511; ++g) {
        STEPX(1, a1.y); STEPX(2, a1.z); STEPX(3, a1.w); STEPX(0, a2.x);
        STEPX(1, a2.y); STEPX(2, a2.z); STEPX(3, a2.w); STEPX(0, a3.x);
        STEPX(1, a3.y); STEPX(2, a3.z); STEPX(3, a3.w); STEPX(0, b0.x);
        STEPX(1, b0.y); STEPX(2, b0.z); STEPX(3, b0.w); STEPX(0, b1.x);
        BOUNDARY();
        a1 = b1; a2 = b2; a3 = b3;
        int off = 16*(g+2); if (off > TT-16) off = TT-16;
        const int4* o4 = (const int4*)(obp + off);
        b0 = o4[0]; b1 = o4[1]; b2 = o4[2]; b3 = o4[3];
    }

    // final partial window: steps 8177..8191 (15 steps)
    STEPX(1, a1.y); STEPX(2, a1.z); STEPX(3, a1.w); STEPX(0, a2.x);
    STEPX(1, a2.y); STEPX(2, a2.z); STEPX(3, a2.w); STEPX(0, a3.x);
    STEPX(1, a3.y); STEPX(2, a3.z); STEPX(3, a3.w); STEPX(0, b0.x);
    STEPX(1, b0.y); STEPX(2, b0.z); STEPX(3, b0.w);

    // final z (cross-wave)
    {
        v2f t = p[0] + p[1];
        float zr = (t.x + t.y) * zmask;
        zr = dpp_add<0x111>(zr); zr = dpp_add<0x112>(zr);
        zr = dpp_add<0x114>(zr); zr = dpp_add<0x118>(zr);
        zr = dpp_add<0x142>(zr); zr = dpp_add<0x143>(zr);
        if (l == 63) box[par][wv][48] = zr;
        __syncthreads();
        float z = ((box[par][0][48] + box[par][1][48]) +
                   (box[par][2][48] + box[par][3][48]));
        ll += __logf(z);
    }
    if (tid == 0) out[b] = ll;
}

extern "C" void kernel_launch(void* const* d_in, const int* in_sizes, int n_in,
                              void* d_out, int out_size, void* d_ws, size_t ws_size,
                              hipStream_t stream)
{
    const float* x  = (const float*)d_in[0];   // inputs [32,8192,101]
    const float* ik = (const float*)d_in[1];   // init_kernel [4]
    const float* tk = (const float*)d_in[2];   // transition_kernel [1836]
    const float* ek = (const float*)d_in[3];   // emission_kernel [58656]
    float* out = (float*)d_out;

    char* ws = (char*)d_ws;
    float*  wIn2  = (float*)(ws + WIN_OFF);
    float*  Ivec  = (float*)(ws + IV_OFF);
    float*  emisP = (float*)(ws + EMIS_OFF);
    int*    obs   = (int*)(ws + OBS_OFF);

    hipLaunchKernelGGL(prep_tables, dim3(3), dim3(256), 0, stream, tk, ik, wIn2, Ivec);
    hipLaunchKernelGGL(prep_emis4, dim3((4*100*SPW + 255)/256), dim3(256), 0, stream,
                       ek, emisP);
    hipLaunchKernelGGL(extract_obs, dim3((NB*TT + 3)/4), dim3(256), 0, stream, x, obs);
    hipLaunchKernelGGL(forward, dim3(NB), dim3(256), 0, stream,
                       emisP, (const float4*)wIn2, Ivec, obs, out);
}